// Round 9
// baseline (94.634 us; speedup 1.0000x reference)
//
#include <hip/hip_runtime.h>
#include <math.h>

#define C_ 128
#define N_ 16384

// ws layout (float offsets)
#define WS_Z    0                          // 8*128
#define WS_CTX  1024                       // 8*4*32*32
#define WS_BMAT 33792                      // (unused)
#define WS_A    164864                     // 8*128*128
#define WS_PCTX 295936                     // 1024 slots * 4096
#define WS_PZ   (WS_PCTX + 1024*4096)      // 512 blocks * 128
#define WS_END  (WS_PZ + 512*128)

typedef __attribute__((ext_vector_type(8))) short bf16x8;
typedef __attribute__((ext_vector_type(4))) float f32x4;
typedef __attribute__((ext_vector_type(4))) unsigned int u32x4;
typedef __attribute__((ext_vector_type(2))) unsigned int u32x2;

__device__ __forceinline__ unsigned int pkbf(float a, float b) {
  unsigned int r;
  asm("v_cvt_pk_bf16_f32 %0, %1, %2" : "=v"(r) : "v"(a), "v"(b));
  return r;
}

__device__ __forceinline__ bf16x8 make_frag(float4 u, float4 v) {
  u32x4 q = {pkbf(u.x, u.y), pkbf(u.z, u.w), pkbf(v.x, v.y), pkbf(v.z, v.w)};
  return *(bf16x8*)&q;
}

__device__ __forceinline__ bf16x8 lds_frag16(const unsigned short* p) {
  u32x4 q = *(const u32x4*)p;
  return *(bf16x8*)&q;
}

__device__ __forceinline__ void load4(const float* p, float* o) {
  float4 v = *(const float4*)p;
  o[0] = v.x; o[1] = v.y; o[2] = v.z; o[3] = v.w;
}

// xs tile addressing: [64 n-rows][136 u16 c-cols], stride 272 B.
// XOR byte bits 4-5 with row bits 4-5: reads (row>>4 const per quarter)
// unaffected; writes spread 8-way->2-way (free). See R6 derivation.
__device__ __forceinline__ void* xsa(void* base, int row, int col_bytes) {
  return (void*)((char*)base + row * 272 + (col_bytes ^ (((row >> 4) & 3) << 4)));
}

// ---------------------------------------------------------------------------
// K1: per (b, 256-n chunk), 512 thr / 8 waves. Wave (h = w&3, t = w>>2):
//   t=0 -> K rows of head h, t=1 -> V rows. KV^T = x^T W^T via swapped MFMA;
//   ek = exp(K); ctx_h += ek_h @ v_h^T (n-half t per wave).
// ---------------------------------------------------------------------------
template<bool ATOMIC>
__global__ __launch_bounds__(512, 2) void k1_kv_ctx(const float* __restrict__ x,
                                                    const float* __restrict__ wqkv,
                                                    float* __restrict__ ws) {
  __shared__ __attribute__((aligned(16))) unsigned short xs[64][136];     // 17.0 KB
  __shared__ __attribute__((aligned(16))) unsigned short ekv[2][128][72]; // 36.9 KB
  const int tid  = threadIdx.x;
  const int wave = tid >> 6;
  const int l15  = tid & 15;
  const int l4   = (tid >> 4) & 3;
  const int b    = blockIdx.y;
  const int j    = blockIdx.x;          // n-chunk 0..63
  const int h    = wave & 3;            // head
  const int t    = wave >> 2;           // 0 = K rows, 1 = V rows
  const int kvrow0 = h * 32 + t * 128;  // row within 256 KV rows
  const float* xb = x + (size_t)b * ((size_t)C_ * N_);

  const int sn4 = tid & 15;             // n-quad
  const int scq = tid >> 4;             // c-quad 0..31

  // W fragments pinned in registers (32 VGPR)
  bf16x8 wf[2][4];
  #pragma unroll
  for (int mi = 0; mi < 2; ++mi)
    #pragma unroll
    for (int ki = 0; ki < 4; ++ki) {
      const float* p = wqkv + (size_t)(128 + kvrow0 + mi * 16 + l15) * C_ + ki * 32 + l4 * 8;
      wf[mi][ki] = make_frag(*(const float4*)p, *(const float4*)(p + 4));
    }

  // prologue: stage subtile 0
  {
    float va[4][4];
    #pragma unroll
    for (int r = 0; r < 4; ++r)
      load4(xb + (size_t)(scq * 4 + r) * N_ + j * 256 + sn4 * 4, va[r]);
    #pragma unroll
    for (int i = 0; i < 4; ++i) {
      u32x2 w = {pkbf(va[0][i], va[1][i]), pkbf(va[2][i], va[3][i])};
      *(u32x2*)xsa(xs, sn4 * 4 + i, scq * 8) = w;
    }
  }
  __syncthreads();

  const f32x4 z4 = {0.f, 0.f, 0.f, 0.f};
  f32x4 ctxacc[2][2];
  #pragma unroll
  for (int i = 0; i < 2; ++i)
    #pragma unroll
    for (int jj = 0; jj < 2; ++jj) ctxacc[i][jj] = z4;
  float zacc[2] = {0.f, 0.f};

  for (int st = 0; st < 4; ++st) {
    // prefetch next subtile into registers (lands after ctx MFMA)
    float pf[4][4];
    if (st < 3) {
      const int nbn = j * 256 + (st + 1) * 64;
      #pragma unroll
      for (int r = 0; r < 4; ++r)
        load4(xb + (size_t)(scq * 4 + r) * N_ + nbn + sn4 * 4, pf[r]);
    }

    // KV^T: two ni-halves to cap register pressure
    #pragma unroll
    for (int half = 0; half < 2; ++half) {
      f32x4 acc[2][2];   // [ni2][mi]
      #pragma unroll
      for (int a = 0; a < 2; ++a)
        #pragma unroll
        for (int m = 0; m < 2; ++m) acc[a][m] = z4;
      #pragma unroll
      for (int ki = 0; ki < 4; ++ki) {
        bf16x8 bfr[2];
        #pragma unroll
        for (int ni2 = 0; ni2 < 2; ++ni2)
          bfr[ni2] = lds_frag16((const unsigned short*)
              xsa(xs, half * 32 + ni2 * 16 + l15, ki * 64 + l4 * 16));
        __builtin_amdgcn_s_setprio(1);
        #pragma unroll
        for (int ni2 = 0; ni2 < 2; ++ni2)
          #pragma unroll
          for (int mi = 0; mi < 2; ++mi)
            acc[ni2][mi] = __builtin_amdgcn_mfma_f32_16x16x32_bf16(
                bfr[ni2], wf[mi][ki], acc[ni2][mi], 0, 0, 0);
        __builtin_amdgcn_s_setprio(0);
      }
      #pragma unroll
      for (int ni2 = 0; ni2 < 2; ++ni2)
        #pragma unroll
        for (int mi = 0; mi < 2; ++mi) {
          float e0, e1, e2, e3;
          if (t == 0) {
            e0 = __expf(acc[ni2][mi][0]); e1 = __expf(acc[ni2][mi][1]);
            e2 = __expf(acc[ni2][mi][2]); e3 = __expf(acc[ni2][mi][3]);
            zacc[mi] += (e0 + e1) + (e2 + e3);
          } else {
            e0 = acc[ni2][mi][0]; e1 = acc[ni2][mi][1];
            e2 = acc[ni2][mi][2]; e3 = acc[ni2][mi][3];
          }
          u32x2 w = {pkbf(e0, e1), pkbf(e2, e3)};
          *(u32x2*)&ekv[t][h * 32 + mi * 16 + l15][(half * 2 + ni2) * 16 + l4 * 4] = w;
        }
    }
    __syncthreads();     // ekv ready

    // ctx_h[d][e] += ek_h[d][n] * v_h[e][n] over this wave's n-half t
    {
      bf16x8 af2[2], bv2[2];
      #pragma unroll
      for (int m2 = 0; m2 < 2; ++m2)
        af2[m2] = lds_frag16(&ekv[0][h * 32 + m2 * 16 + l15][t * 32 + l4 * 8]);
      #pragma unroll
      for (int n2 = 0; n2 < 2; ++n2)
        bv2[n2] = lds_frag16(&ekv[1][h * 32 + n2 * 16 + l15][t * 32 + l4 * 8]);
      __builtin_amdgcn_s_setprio(1);
      #pragma unroll
      for (int m2 = 0; m2 < 2; ++m2)
        #pragma unroll
        for (int n2 = 0; n2 < 2; ++n2)
          ctxacc[m2][n2] = __builtin_amdgcn_mfma_f32_16x16x32_bf16(
              af2[m2], bv2[n2], ctxacc[m2][n2], 0, 0, 0);
      __builtin_amdgcn_s_setprio(0);
    }

    // write prefetched subtile into xs (KV readers done at barrier above)
    if (st < 3) {
      #pragma unroll
      for (int i = 0; i < 4; ++i) {
        u32x2 w = {pkbf(pf[0][i], pf[1][i]), pkbf(pf[2][i], pf[3][i])};
        *(u32x2*)xsa(xs, sn4 * 4 + i, scq * 8) = w;
      }
    }
    __syncthreads();     // xs ready for next KV; ekv consumed
  }

  // epilogue
  if (!ATOMIC) {
    float* ps = ws + WS_PCTX + (size_t)((b * 64 + j) * 2 + t) * 4096 + h * 1024;
    #pragma unroll
    for (int m2 = 0; m2 < 2; ++m2)
      #pragma unroll
      for (int n2 = 0; n2 < 2; ++n2)
        #pragma unroll
        for (int r = 0; r < 4; ++r)
          ps[(m2 * 16 + l4 * 4 + r) * 32 + n2 * 16 + l15] = ctxacc[m2][n2][r];
  } else {
    float* ctx = ws + WS_CTX + (size_t)(b * 4 + h) * 1024;
    #pragma unroll
    for (int m2 = 0; m2 < 2; ++m2)
      #pragma unroll
      for (int n2 = 0; n2 < 2; ++n2)
        #pragma unroll
        for (int r = 0; r < 4; ++r)
          atomicAdd(&ctx[(m2 * 16 + l4 * 4 + r) * 32 + n2 * 16 + l15],
                    ctxacc[m2][n2][r]);
  }
  if (t == 0) {
    #pragma unroll
    for (int mi = 0; mi < 2; ++mi) {
      float z = zacc[mi];
      z += __shfl_xor(z, 16);
      z += __shfl_xor(z, 32);
      if ((tid & 48) == 0) {
        int row = h * 32 + mi * 16 + l15;
        if (!ATOMIC)
          ws[WS_PZ + (size_t)(b * 64 + j) * 128 + row] = z;
        else
          atomicAdd(&ws[WS_Z + b * 128 + row], z);
      }
    }
  }
}

// ---------------------------------------------------------------------------
// K1c: wide partial reduction (128 blocks), coalesced float4 streams.
// ---------------------------------------------------------------------------
__global__ __launch_bounds__(256) void k1c(float* __restrict__ ws) {
  __shared__ float4 part[4][64];
  const int tid = threadIdx.x;
  const int eq = blockIdx.x;   // 0..3
  const int h  = blockIdx.y;   // 0..3
  const int b  = blockIdx.z;   // 0..7
  const int f4 = tid & 63;
  const int p  = tid >> 6;

  const float* base = ws + WS_PCTX + (size_t)(b * 128) * 4096
                         + h * 1024 + eq * 256 + f4 * 4;
  float4 s = {0.f, 0.f, 0.f, 0.f};
  #pragma unroll 8
  for (int q = 0; q < 32; ++q) {
    float4 v = *(const float4*)(base + (size_t)(p * 32 + q) * 4096);
    s.x += v.x; s.y += v.y; s.z += v.z; s.w += v.w;
  }
  part[p][f4] = s;

  if (eq == 0 && tid < 32) {
    const float* pz = ws + WS_PZ + (size_t)(b * 64) * 128 + h * 32 + tid;
    float z = 0.f;
    #pragma unroll 8
    for (int q = 0; q < 64; ++q) z += pz[(size_t)q * 128];
    ws[WS_Z + b * 128 + h * 32 + tid] = z;
  }
  __syncthreads();

  if (tid < 64) {
    float4 a = part[0][tid], c = part[1][tid], d = part[2][tid], e = part[3][tid];
    float4 o;
    o.x = (a.x + c.x) + (d.x + e.x);
    o.y = (a.y + c.y) + (d.y + e.y);
    o.z = (a.z + c.z) + (d.z + e.z);
    o.w = (a.w + c.w) + (d.w + e.w);
    *(float4*)(ws + WS_CTX + (size_t)(b * 4 + h) * 1024 + eq * 256 + tid * 4) = o;
  }
}

// ---------------------------------------------------------------------------
// K2 (fused): per (oq, b): build Bmat[b] in LDS from reduced ctx/Z, then
//   A[b] rows oq*32..+31 = w_out rows @ Bmat[b].
// ---------------------------------------------------------------------------
__global__ __launch_bounds__(256) void k2(const float* __restrict__ w_qkv,
                                          const float* __restrict__ w_out,
                                          float* __restrict__ ws) {
  __shared__ float bs[128][132];
  __shared__ float wqs[32][128];
  __shared__ float wos[32][132];
  __shared__ float cn[32][33];
  const int tid = threadIdx.x;
  const int oq = blockIdx.x, b = blockIdx.y;

  for (int h = 0; h < 4; ++h) {
    if (h) __syncthreads();
    const float* Z   = ws + WS_Z + b * 128 + h * 32;
    const float* ctx = ws + WS_CTX + ((b * 4 + h) * 32) * 32;
    #pragma unroll
    for (int k = 0; k < 4; ++k) {
      int idx = tid + k * 256;
      int d = idx >> 5, e = idx & 31;
      cn[d][e] = ctx[d * 32 + e] / Z[d];
    }
    #pragma unroll
    for (int k = 0; k < 4; ++k) {
      int idx = tid + k * 256;
      int d = idx >> 5, f4 = idx & 31;
      *(float4*)&wqs[d][f4 * 4] = *(const float4*)(w_qkv + (h * 32 + d) * 128 + f4 * 4);
    }
    __syncthreads();
    const int e = tid >> 3, cs = (tid & 7) * 16;
    float s[16];
    #pragma unroll
    for (int jj = 0; jj < 16; ++jj) s[jj] = 0.f;
    for (int d = 0; d < 32; ++d) {
      float v = cn[d][e];
      #pragma unroll
      for (int jj = 0; jj < 16; ++jj) s[jj] = fmaf(v, wqs[d][cs + jj], s[jj]);
    }
    #pragma unroll
    for (int jj = 0; jj < 16; ++jj) bs[h * 32 + e][cs + jj] = s[jj];
  }

  __syncthreads();
  #pragma unroll
  for (int k = 0; k < 4; ++k) {
    int idx = tid + k * 256;
    int r = idx >> 5, f4 = idx & 31;
    *(float4*)&wos[r][f4 * 4] = *(const float4*)(w_out + (oq * 32 + r) * 128 + f4 * 4);
  }
  __syncthreads();
  const int ol = tid >> 3, cq = (tid & 7) * 16;
  float s[16];
  #pragma unroll
  for (int jj = 0; jj < 16; ++jj) s[jj] = 0.f;
  for (int eg = 0; eg < 128; ++eg) {
    float w = wos[ol][eg];
    #pragma unroll
    for (int jj = 0; jj < 16; ++jj) s[jj] = fmaf(w, bs[eg][cq + jj], s[jj]);
  }
  float* A = ws + WS_A + ((size_t)b * 128 + oq * 32 + ol) * 128;
  #pragma unroll
  for (int jj = 0; jj < 16; ++jj) A[cq + jj] = s[jj];
}

// ---------------------------------------------------------------------------
// K3: y[b] = A[b] @ x[b] + b_out. 512 thr / 8 waves, 256-n chunk per block,
//   wave owns 16 y-rows. Double-buffered xs + register prefetch.
// ---------------------------------------------------------------------------
__global__ __launch_bounds__(512, 2) void k3(const float* __restrict__ x,
                                             const float* __restrict__ bout,
                                             const float* __restrict__ ws,
                                             float* __restrict__ y) {
  __shared__ __attribute__((aligned(16))) unsigned short xs2[2][64][136]; // 34.8 KB
  const int tid  = threadIdx.x;
  const int wave = tid >> 6;
  const int l15  = tid & 15;
  const int l4   = (tid >> 4) & 3;
  const int b    = blockIdx.y;
  const int n0   = blockIdx.x * 256;
  const float* xb = x + (size_t)b * ((size_t)C_ * N_);
  const float* A  = ws + WS_A + (size_t)b * 128 * 128;

  const int sn4 = tid & 15;
  const int scq = tid >> 4;             // 0..31

  bf16x8 af[4];
  #pragma unroll
  for (int ki = 0; ki < 4; ++ki) {
    const float* p = A + (size_t)(wave * 16 + l15) * 128 + ki * 32 + l4 * 8;
    af[ki] = make_frag(*(const float4*)p, *(const float4*)(p + 4));
  }
  const float bias = bout[wave * 16 + l15];

  // stage subtile 0 (one 4c x 4n task per thread)
  {
    float va[4][4];
    #pragma unroll
    for (int r = 0; r < 4; ++r)
      load4(xb + (size_t)(scq * 4 + r) * N_ + n0 + sn4 * 4, va[r]);
    #pragma unroll
    for (int i = 0; i < 4; ++i) {
      u32x2 w = {pkbf(va[0][i], va[1][i]), pkbf(va[2][i], va[3][i])};
      *(u32x2*)xsa(&xs2[0][0][0], sn4 * 4 + i, scq * 8) = w;
    }
  }
  __syncthreads();

  const f32x4 z4 = {0.f, 0.f, 0.f, 0.f};
  float* yb = y + (size_t)b * ((size_t)128 * N_);

  for (int st = 0; st < 4; ++st) {
    const int nb = n0 + st * 64;

    // register prefetch of next subtile (overlaps MFMA)
    float pf[4][4];
    if (st < 3) {
      #pragma unroll
      for (int r = 0; r < 4; ++r)
        load4(xb + (size_t)(scq * 4 + r) * N_ + nb + 64 + sn4 * 4, pf[r]);
    }

    f32x4 acc[4];
    #pragma unroll
    for (int ni = 0; ni < 4; ++ni) acc[ni] = z4;
    #pragma unroll
    for (int ki = 0; ki < 4; ++ki) {
      bf16x8 bfr[4];
      #pragma unroll
      for (int ni = 0; ni < 4; ++ni)
        bfr[ni] = lds_frag16((const unsigned short*)
            xsa(&xs2[st & 1][0][0], ni * 16 + l15, ki * 64 + l4 * 16));
      #pragma unroll
      for (int ni = 0; ni < 4; ++ni)
        acc[ni] = __builtin_amdgcn_mfma_f32_16x16x32_bf16(
            bfr[ni], af[ki], acc[ni], 0, 0, 0);
    }

    // store: lane holds y row wave*16+l15, 4 consecutive n
    #pragma unroll
    for (int ni = 0; ni < 4; ++ni) {
      float4 o;
      o.x = acc[ni][0] + bias;
      o.y = acc[ni][1] + bias;
      o.z = acc[ni][2] + bias;
      o.w = acc[ni][3] + bias;
      *(float4*)(yb + (size_t)(wave * 16 + l15) * N_ + nb + ni * 16 + l4 * 4) = o;
    }

    // write prefetched subtile into the OTHER buffer (not being read)
    if (st < 3) {
      #pragma unroll
      for (int i = 0; i < 4; ++i) {
        u32x2 w = {pkbf(pf[0][i], pf[1][i]), pkbf(pf[2][i], pf[3][i])};
        *(u32x2*)xsa(&xs2[(st + 1) & 1][0][0], sn4 * 4 + i, scq * 8) = w;
      }
      __syncthreads();   // one barrier per subtile
    }
  }
}

extern "C" void kernel_launch(void* const* d_in, const int* in_sizes, int n_in,
                              void* d_out, int out_size, void* d_ws, size_t ws_size,
                              hipStream_t stream) {
  const float* x     = (const float*)d_in[0];
  const float* w_qkv = (const float*)d_in[1];
  const float* w_out = (const float*)d_in[2];
  const float* b_out = (const float*)d_in[3];
  float* y  = (float*)d_out;
  float* ws = (float*)d_ws;

  const bool partial = ws_size >= (size_t)WS_END * sizeof(float);
  if (partial) {
    // ATTRIBUTION PROBE (this round only): k1 launched twice. The second run
    // writes byte-identical partials (pure stores, no atomics) -> output
    // unchanged, deterministic. t(k1_warm) = dur_us(this) - dur_us(R8=75.2).
    k1_kv_ctx<false><<<dim3(64, 8), 512, 0, stream>>>(x, w_qkv, ws);
    k1_kv_ctx<false><<<dim3(64, 8), 512, 0, stream>>>(x, w_qkv, ws);
    k1c<<<dim3(4, 4, 8), 256, 0, stream>>>(ws);
  } else {
    hipMemsetAsync(ws, 0, (1024 + 32768) * sizeof(float), stream);
    k1_kv_ctx<true><<<dim3(64, 8), 512, 0, stream>>>(x, w_qkv, ws);
  }
  k2<<<dim3(4, 8), 256, 0, stream>>>(w_qkv, w_out, ws);
  k3<<<dim3(64, 8), 512, 0, stream>>>(x, b_out, ws, y);
}

// Round 10
// 73.164 us; speedup vs baseline: 1.2935x; 1.2935x over previous
//
#include <hip/hip_runtime.h>
#include <math.h>

#define C_ 128
#define N_ 16384

// ws layout (float offsets)
#define WS_Z    0                          // 8*128
#define WS_CTX  1024                       // 8*4*32*32
#define WS_A    164864                     // 8*128*128
#define WS_PCTX 295936                     // 512 slots * 4096 (t pre-combined)
#define WS_PZ   (WS_PCTX + 512*4096)       // 512 slots * 128
#define WS_END  (WS_PZ + 512*128)

typedef __attribute__((ext_vector_type(8))) short bf16x8;
typedef __attribute__((ext_vector_type(4))) float f32x4;
typedef __attribute__((ext_vector_type(4))) unsigned int u32x4;
typedef __attribute__((ext_vector_type(2))) unsigned int u32x2;

__device__ __forceinline__ unsigned int pkbf(float a, float b) {
  unsigned int r;
  asm("v_cvt_pk_bf16_f32 %0, %1, %2" : "=v"(r) : "v"(a), "v"(b));
  return r;
}

__device__ __forceinline__ bf16x8 make_frag(float4 u, float4 v) {
  u32x4 q = {pkbf(u.x, u.y), pkbf(u.z, u.w), pkbf(v.x, v.y), pkbf(v.z, v.w)};
  return *(bf16x8*)&q;
}

__device__ __forceinline__ bf16x8 lds_frag16(const unsigned short* p) {
  u32x4 q = *(const u32x4*)p;
  return *(bf16x8*)&q;
}

__device__ __forceinline__ void load4(const float* p, float* o) {
  float4 v = *(const float4*)p;
  o[0] = v.x; o[1] = v.y; o[2] = v.z; o[3] = v.w;
}

// xs tile addressing: [64 n-rows][136 u16 c-cols], stride 272 B.
// XOR byte bits 4-5 with row bits 4-5: reads (row>>4 const per quarter)
// unaffected; writes spread 8-way->2-way (free). See R6 derivation.
__device__ __forceinline__ void* xsa(void* base, int row, int col_bytes) {
  return (void*)((char*)base + row * 272 + (col_bytes ^ (((row >> 4) & 3) << 4)));
}

// ---------------------------------------------------------------------------
// K1: per (b, 256-n chunk), 512 thr / 8 waves. Wave (h = w&3, t = w>>2):
//   t=0 -> K rows of head h, t=1 -> V rows. KV^T = x^T W^T via swapped MFMA;
//   ek = exp(K); ctx_h += ek_h @ v_h^T (n-half t per wave).
//   Epilogue: in-block t-combine via LDS -> ONE partial slot per (b,j).
// ---------------------------------------------------------------------------
template<bool ATOMIC>
__global__ __launch_bounds__(512, 2) void k1_kv_ctx(const float* __restrict__ x,
                                                    const float* __restrict__ wqkv,
                                                    float* __restrict__ ws) {
  __shared__ __attribute__((aligned(16))) unsigned short xs[64][136];     // 17.0 KB
  __shared__ __attribute__((aligned(16))) unsigned short ekv[2][128][72]; // 36.9 KB
  const int tid  = threadIdx.x;
  const int wave = tid >> 6;
  const int l15  = tid & 15;
  const int l4   = (tid >> 4) & 3;
  const int b    = blockIdx.y;
  const int j    = blockIdx.x;          // n-chunk 0..63
  const int h    = wave & 3;            // head
  const int t    = wave >> 2;           // 0 = K rows, 1 = V rows
  const int kvrow0 = h * 32 + t * 128;  // row within 256 KV rows
  const float* xb = x + (size_t)b * ((size_t)C_ * N_);

  const int sn4 = tid & 15;             // n-quad
  const int scq = tid >> 4;             // c-quad 0..31

  // W fragments pinned in registers (32 VGPR)
  bf16x8 wf[2][4];
  #pragma unroll
  for (int mi = 0; mi < 2; ++mi)
    #pragma unroll
    for (int ki = 0; ki < 4; ++ki) {
      const float* p = wqkv + (size_t)(128 + kvrow0 + mi * 16 + l15) * C_ + ki * 32 + l4 * 8;
      wf[mi][ki] = make_frag(*(const float4*)p, *(const float4*)(p + 4));
    }

  // prologue: stage subtile 0
  {
    float va[4][4];
    #pragma unroll
    for (int r = 0; r < 4; ++r)
      load4(xb + (size_t)(scq * 4 + r) * N_ + j * 256 + sn4 * 4, va[r]);
    #pragma unroll
    for (int i = 0; i < 4; ++i) {
      u32x2 w = {pkbf(va[0][i], va[1][i]), pkbf(va[2][i], va[3][i])};
      *(u32x2*)xsa(xs, sn4 * 4 + i, scq * 8) = w;
    }
  }
  __syncthreads();

  const f32x4 z4 = {0.f, 0.f, 0.f, 0.f};
  f32x4 ctxacc[2][2];
  #pragma unroll
  for (int i = 0; i < 2; ++i)
    #pragma unroll
    for (int jj = 0; jj < 2; ++jj) ctxacc[i][jj] = z4;
  float zacc[2] = {0.f, 0.f};

  for (int st = 0; st < 4; ++st) {
    // prefetch next subtile into registers (lands after ctx MFMA)
    float pf[4][4];
    if (st < 3) {
      const int nbn = j * 256 + (st + 1) * 64;
      #pragma unroll
      for (int r = 0; r < 4; ++r)
        load4(xb + (size_t)(scq * 4 + r) * N_ + nbn + sn4 * 4, pf[r]);
    }

    // KV^T: two ni-halves to cap register pressure
    #pragma unroll
    for (int half = 0; half < 2; ++half) {
      f32x4 acc[2][2];   // [ni2][mi]
      #pragma unroll
      for (int a = 0; a < 2; ++a)
        #pragma unroll
        for (int m = 0; m < 2; ++m) acc[a][m] = z4;
      #pragma unroll
      for (int ki = 0; ki < 4; ++ki) {
        bf16x8 bfr[2];
        #pragma unroll
        for (int ni2 = 0; ni2 < 2; ++ni2)
          bfr[ni2] = lds_frag16((const unsigned short*)
              xsa(xs, half * 32 + ni2 * 16 + l15, ki * 64 + l4 * 16));
        __builtin_amdgcn_s_setprio(1);
        #pragma unroll
        for (int ni2 = 0; ni2 < 2; ++ni2)
          #pragma unroll
          for (int mi = 0; mi < 2; ++mi)
            acc[ni2][mi] = __builtin_amdgcn_mfma_f32_16x16x32_bf16(
                bfr[ni2], wf[mi][ki], acc[ni2][mi], 0, 0, 0);
        __builtin_amdgcn_s_setprio(0);
      }
      #pragma unroll
      for (int ni2 = 0; ni2 < 2; ++ni2)
        #pragma unroll
        for (int mi = 0; mi < 2; ++mi) {
          float e0, e1, e2, e3;
          if (t == 0) {
            e0 = __expf(acc[ni2][mi][0]); e1 = __expf(acc[ni2][mi][1]);
            e2 = __expf(acc[ni2][mi][2]); e3 = __expf(acc[ni2][mi][3]);
            zacc[mi] += (e0 + e1) + (e2 + e3);
          } else {
            e0 = acc[ni2][mi][0]; e1 = acc[ni2][mi][1];
            e2 = acc[ni2][mi][2]; e3 = acc[ni2][mi][3];
          }
          u32x2 w = {pkbf(e0, e1), pkbf(e2, e3)};
          *(u32x2*)&ekv[t][h * 32 + mi * 16 + l15][(half * 2 + ni2) * 16 + l4 * 4] = w;
        }
    }
    __syncthreads();     // ekv ready

    // ctx_h[d][e] += ek_h[d][n] * v_h[e][n] over this wave's n-half t
    {
      bf16x8 af2[2], bv2[2];
      #pragma unroll
      for (int m2 = 0; m2 < 2; ++m2)
        af2[m2] = lds_frag16(&ekv[0][h * 32 + m2 * 16 + l15][t * 32 + l4 * 8]);
      #pragma unroll
      for (int n2 = 0; n2 < 2; ++n2)
        bv2[n2] = lds_frag16(&ekv[1][h * 32 + n2 * 16 + l15][t * 32 + l4 * 8]);
      __builtin_amdgcn_s_setprio(1);
      #pragma unroll
      for (int m2 = 0; m2 < 2; ++m2)
        #pragma unroll
        for (int n2 = 0; n2 < 2; ++n2)
          ctxacc[m2][n2] = __builtin_amdgcn_mfma_f32_16x16x32_bf16(
              af2[m2], bv2[n2], ctxacc[m2][n2], 0, 0, 0);
      __builtin_amdgcn_s_setprio(0);
    }

    // write prefetched subtile into xs (KV readers done at barrier above)
    if (st < 3) {
      #pragma unroll
      for (int i = 0; i < 4; ++i) {
        u32x2 w = {pkbf(pf[0][i], pf[1][i]), pkbf(pf[2][i], pf[3][i])};
        *(u32x2*)xsa(xs, sn4 * 4 + i, scq * 8) = w;
      }
    }
    __syncthreads();     // xs ready for next KV; ekv consumed
  }

  // epilogue: in-block t-combine (ekv LDS reused as float scratch;
  // stride 36 -> (16*l4 + l15) mod 32 -> 2-way = free)
  {
    float* csh = (float*)ekv;
    if (t == 1) {
      #pragma unroll
      for (int m2 = 0; m2 < 2; ++m2)
        #pragma unroll
        for (int n2 = 0; n2 < 2; ++n2)
          #pragma unroll
          for (int r = 0; r < 4; ++r)
            csh[h * 1152 + (m2 * 16 + l4 * 4 + r) * 36 + n2 * 16 + l15] =
                ctxacc[m2][n2][r];
    }
    __syncthreads();
    if (t == 0) {
      #pragma unroll
      for (int m2 = 0; m2 < 2; ++m2)
        #pragma unroll
        for (int n2 = 0; n2 < 2; ++n2)
          #pragma unroll
          for (int r = 0; r < 4; ++r)
            ctxacc[m2][n2][r] +=
                csh[h * 1152 + (m2 * 16 + l4 * 4 + r) * 36 + n2 * 16 + l15];
      if (!ATOMIC) {
        float* ps = ws + WS_PCTX + (size_t)(b * 64 + j) * 4096 + h * 1024;
        #pragma unroll
        for (int m2 = 0; m2 < 2; ++m2)
          #pragma unroll
          for (int n2 = 0; n2 < 2; ++n2)
            #pragma unroll
            for (int r = 0; r < 4; ++r)
              ps[(m2 * 16 + l4 * 4 + r) * 32 + n2 * 16 + l15] = ctxacc[m2][n2][r];
      } else {
        float* ctx = ws + WS_CTX + (size_t)(b * 4 + h) * 1024;
        #pragma unroll
        for (int m2 = 0; m2 < 2; ++m2)
          #pragma unroll
          for (int n2 = 0; n2 < 2; ++n2)
            #pragma unroll
            for (int r = 0; r < 4; ++r)
              atomicAdd(&ctx[(m2 * 16 + l4 * 4 + r) * 32 + n2 * 16 + l15],
                        ctxacc[m2][n2][r]);
      }
      // Z partials
      #pragma unroll
      for (int mi = 0; mi < 2; ++mi) {
        float z = zacc[mi];
        z += __shfl_xor(z, 16);
        z += __shfl_xor(z, 32);
        if ((tid & 48) == 0) {
          int row = h * 32 + mi * 16 + l15;
          if (!ATOMIC)
            ws[WS_PZ + (size_t)(b * 64 + j) * 128 + row] = z;
          else
            atomicAdd(&ws[WS_Z + b * 128 + row], z);
        }
      }
    }
  }
}

// ---------------------------------------------------------------------------
// K1c: wide partial reduction (128 blocks) over 64 slots/b, coalesced float4.
// ---------------------------------------------------------------------------
__global__ __launch_bounds__(256) void k1c(float* __restrict__ ws) {
  __shared__ float4 part[4][64];
  const int tid = threadIdx.x;
  const int eq = blockIdx.x;   // 0..3
  const int h  = blockIdx.y;   // 0..3
  const int b  = blockIdx.z;   // 0..7
  const int f4 = tid & 63;
  const int p  = tid >> 6;

  const float* base = ws + WS_PCTX + (size_t)(b * 64) * 4096
                         + h * 1024 + eq * 256 + f4 * 4;
  float4 s = {0.f, 0.f, 0.f, 0.f};
  #pragma unroll 8
  for (int q = 0; q < 16; ++q) {
    float4 v = *(const float4*)(base + (size_t)(p * 16 + q) * 4096);
    s.x += v.x; s.y += v.y; s.z += v.z; s.w += v.w;
  }
  part[p][f4] = s;

  if (eq == 0 && tid < 32) {
    const float* pz = ws + WS_PZ + (size_t)(b * 64) * 128 + h * 32 + tid;
    float z = 0.f;
    #pragma unroll 8
    for (int q = 0; q < 64; ++q) z += pz[(size_t)q * 128];
    ws[WS_Z + b * 128 + h * 32 + tid] = z;
  }
  __syncthreads();

  if (tid < 64) {
    float4 a = part[0][tid], c = part[1][tid], d = part[2][tid], e = part[3][tid];
    float4 o;
    o.x = (a.x + c.x) + (d.x + e.x);
    o.y = (a.y + c.y) + (d.y + e.y);
    o.z = (a.z + c.z) + (d.z + e.z);
    o.w = (a.w + c.w) + (d.w + e.w);
    *(float4*)(ws + WS_CTX + (size_t)(b * 4 + h) * 1024 + eq * 256 + tid * 4) = o;
  }
}

// ---------------------------------------------------------------------------
// K2 (fused): per (oq, b): build Bmat[b] in LDS from reduced ctx/Z, then
//   A[b] rows oq*32..+31 = w_out rows @ Bmat[b].
// ---------------------------------------------------------------------------
__global__ __launch_bounds__(256) void k2(const float* __restrict__ w_qkv,
                                          const float* __restrict__ w_out,
                                          float* __restrict__ ws) {
  __shared__ float bs[128][132];
  __shared__ float wqs[32][128];
  __shared__ float wos[32][132];
  __shared__ float cn[32][33];
  const int tid = threadIdx.x;
  const int oq = blockIdx.x, b = blockIdx.y;

  for (int h = 0; h < 4; ++h) {
    if (h) __syncthreads();
    const float* Z   = ws + WS_Z + b * 128 + h * 32;
    const float* ctx = ws + WS_CTX + ((b * 4 + h) * 32) * 32;
    #pragma unroll
    for (int k = 0; k < 4; ++k) {
      int idx = tid + k * 256;
      int d = idx >> 5, e = idx & 31;
      cn[d][e] = ctx[d * 32 + e] / Z[d];
    }
    #pragma unroll
    for (int k = 0; k < 4; ++k) {
      int idx = tid + k * 256;
      int d = idx >> 5, f4 = idx & 31;
      *(float4*)&wqs[d][f4 * 4] = *(const float4*)(w_qkv + (h * 32 + d) * 128 + f4 * 4);
    }
    __syncthreads();
    const int e = tid >> 3, cs = (tid & 7) * 16;
    float s[16];
    #pragma unroll
    for (int jj = 0; jj < 16; ++jj) s[jj] = 0.f;
    for (int d = 0; d < 32; ++d) {
      float v = cn[d][e];
      #pragma unroll
      for (int jj = 0; jj < 16; ++jj) s[jj] = fmaf(v, wqs[d][cs + jj], s[jj]);
    }
    #pragma unroll
    for (int jj = 0; jj < 16; ++jj) bs[h * 32 + e][cs + jj] = s[jj];
  }

  __syncthreads();
  #pragma unroll
  for (int k = 0; k < 4; ++k) {
    int idx = tid + k * 256;
    int r = idx >> 5, f4 = idx & 31;
    *(float4*)&wos[r][f4 * 4] = *(const float4*)(w_out + (oq * 32 + r) * 128 + f4 * 4);
  }
  __syncthreads();
  const int ol = tid >> 3, cq = (tid & 7) * 16;
  float s[16];
  #pragma unroll
  for (int jj = 0; jj < 16; ++jj) s[jj] = 0.f;
  for (int eg = 0; eg < 128; ++eg) {
    float w = wos[ol][eg];
    #pragma unroll
    for (int jj = 0; jj < 16; ++jj) s[jj] = fmaf(w, bs[eg][cq + jj], s[jj]);
  }
  float* A = ws + WS_A + ((size_t)b * 128 + oq * 32 + ol) * 128;
  #pragma unroll
  for (int jj = 0; jj < 16; ++jj) A[cq + jj] = s[jj];
}

// ---------------------------------------------------------------------------
// K3: y[b] = A[b] @ x[b] + b_out. 512 thr / 8 waves, 256-n chunk per block.
//   Store-drain fix: ds_write of prefetched subtile issued BEFORE y-stores
//   (its vmcnt wait then covers only the loads; stores retire behind barrier).
// ---------------------------------------------------------------------------
__global__ __launch_bounds__(512, 2) void k3(const float* __restrict__ x,
                                             const float* __restrict__ bout,
                                             const float* __restrict__ ws,
                                             float* __restrict__ y) {
  __shared__ __attribute__((aligned(16))) unsigned short xs2[2][64][136]; // 34.8 KB
  const int tid  = threadIdx.x;
  const int wave = tid >> 6;
  const int l15  = tid & 15;
  const int l4   = (tid >> 4) & 3;
  const int b    = blockIdx.y;
  const int n0   = blockIdx.x * 256;
  const float* xb = x + (size_t)b * ((size_t)C_ * N_);
  const float* A  = ws + WS_A + (size_t)b * 128 * 128;

  const int sn4 = tid & 15;
  const int scq = tid >> 4;             // 0..31

  bf16x8 af[4];
  #pragma unroll
  for (int ki = 0; ki < 4; ++ki) {
    const float* p = A + (size_t)(wave * 16 + l15) * 128 + ki * 32 + l4 * 8;
    af[ki] = make_frag(*(const float4*)p, *(const float4*)(p + 4));
  }
  const float bias = bout[wave * 16 + l15];

  // stage subtile 0 (one 4c x 4n task per thread)
  {
    float va[4][4];
    #pragma unroll
    for (int r = 0; r < 4; ++r)
      load4(xb + (size_t)(scq * 4 + r) * N_ + n0 + sn4 * 4, va[r]);
    #pragma unroll
    for (int i = 0; i < 4; ++i) {
      u32x2 w = {pkbf(va[0][i], va[1][i]), pkbf(va[2][i], va[3][i])};
      *(u32x2*)xsa(&xs2[0][0][0], sn4 * 4 + i, scq * 8) = w;
    }
  }
  __syncthreads();

  const f32x4 z4 = {0.f, 0.f, 0.f, 0.f};
  float* yb = y + (size_t)b * ((size_t)128 * N_);

  for (int st = 0; st < 4; ++st) {
    const int nb = n0 + st * 64;

    // register prefetch of next subtile (overlaps MFMA)
    float pf[4][4];
    if (st < 3) {
      #pragma unroll
      for (int r = 0; r < 4; ++r)
        load4(xb + (size_t)(scq * 4 + r) * N_ + nb + 64 + sn4 * 4, pf[r]);
    }

    f32x4 acc[4];
    #pragma unroll
    for (int ni = 0; ni < 4; ++ni) acc[ni] = z4;
    #pragma unroll
    for (int ki = 0; ki < 4; ++ki) {
      bf16x8 bfr[4];
      #pragma unroll
      for (int ni = 0; ni < 4; ++ni)
        bfr[ni] = lds_frag16((const unsigned short*)
            xsa(&xs2[st & 1][0][0], ni * 16 + l15, ki * 64 + l4 * 16));
      #pragma unroll
      for (int ni = 0; ni < 4; ++ni)
        acc[ni] = __builtin_amdgcn_mfma_f32_16x16x32_bf16(
            bfr[ni], af[ki], acc[ni], 0, 0, 0);
    }

    // write prefetched subtile into the OTHER buffer BEFORE y-stores
    if (st < 3) {
      #pragma unroll
      for (int i = 0; i < 4; ++i) {
        u32x2 w = {pkbf(pf[0][i], pf[1][i]), pkbf(pf[2][i], pf[3][i])};
        *(u32x2*)xsa(&xs2[(st + 1) & 1][0][0], sn4 * 4 + i, scq * 8) = w;
      }
    }

    // store: lane holds y row wave*16+l15, 4 consecutive n
    #pragma unroll
    for (int ni = 0; ni < 4; ++ni) {
      float4 o;
      o.x = acc[ni][0] + bias;
      o.y = acc[ni][1] + bias;
      o.z = acc[ni][2] + bias;
      o.w = acc[ni][3] + bias;
      *(float4*)(yb + (size_t)(wave * 16 + l15) * N_ + nb + ni * 16 + l4 * 4) = o;
    }

    if (st < 3) __syncthreads();
  }
}

extern "C" void kernel_launch(void* const* d_in, const int* in_sizes, int n_in,
                              void* d_out, int out_size, void* d_ws, size_t ws_size,
                              hipStream_t stream) {
  const float* x     = (const float*)d_in[0];
  const float* w_qkv = (const float*)d_in[1];
  const float* w_out = (const float*)d_in[2];
  const float* b_out = (const float*)d_in[3];
  float* y  = (float*)d_out;
  float* ws = (float*)d_ws;

  const bool partial = ws_size >= (size_t)WS_END * sizeof(float);
  if (partial) {
    k1_kv_ctx<false><<<dim3(64, 8), 512, 0, stream>>>(x, w_qkv, ws);
    k1c<<<dim3(4, 4, 8), 256, 0, stream>>>(ws);
  } else {
    hipMemsetAsync(ws, 0, (1024 + 32768) * sizeof(float), stream);
    k1_kv_ctx<true><<<dim3(64, 8), 512, 0, stream>>>(x, w_qkv, ws);
  }
  k2<<<dim3(4, 8), 256, 0, stream>>>(w_qkv, w_out, ws);
  k3<<<dim3(64, 8), 512, 0, stream>>>(x, b_out, ws, y);
}